// Round 13
// baseline (632.295 us; speedup 1.0000x reference)
//
#include <hip/hip_runtime.h>
#include <math.h>

#define N_NODES   50000
#define N_EDGES   640000
#define N_GRAPHS  500
#define DIM       128
#define N_CLASSES 10

#define HB          64      // edge slices for privatized histogram
#define CHUNK_NODES 25000   // nodes per chunk (2 chunks cover 50000)
#define CHUNK_WORDS 12500   // packed uint16-pair words per chunk (50 KB LDS)

// ---------------------------------------------------------------- utilities

__global__ void zero_kernel(int* __restrict__ p, int n) {
    int i = blockIdx.x * blockDim.x + threadIdx.x;
    if (i < n) p[i] = 0;
}

// Privatized histogram: grid (HB, 2 chunks, 2 arrays). Each block histograms
// its 10K-edge slice for one node-chunk of one array into packed LDS
// counters (2 x uint16 per word), then dumps the partial to global.
__global__ __launch_bounds__(256) void hist_kernel(
    const int* __restrict__ src, const int* __restrict__ dst,
    unsigned* __restrict__ partials /* [2 arr][2 chunk][HB][CHUNK_WORDS] */)
{
    __shared__ unsigned hcnt[CHUNK_WORDS];
    int t = threadIdx.x;
    for (int i = t; i < CHUNK_WORDS; i += 256) hcnt[i] = 0;
    __syncthreads();
    const int* arr = blockIdx.z ? dst : src;
    int lo = blockIdx.y * CHUNK_NODES;
    int per = N_EDGES / HB;                  // 10000
    int beg = blockIdx.x * per;
    for (int i = beg + t; i < beg + per; i += 256) {
        int v = arr[i] - lo;
        if ((unsigned)v < (unsigned)CHUNK_NODES)
            atomicAdd(&hcnt[v >> 1], (v & 1) ? 0x10000u : 1u);
    }
    __syncthreads();
    unsigned* outp = partials +
        (((size_t)blockIdx.z * 2 + blockIdx.y) * HB + blockIdx.x) * CHUNK_WORDS;
    for (int i = t; i < CHUNK_WORDS; i += 256) outp[i] = hcnt[i];
}

// Sum partials -> deg_in (for the scan) + both norms (deg_out never stored).
__global__ __launch_bounds__(256) void hist_reduce(
    const unsigned* __restrict__ partials, int* __restrict__ deg_in,
    float* __restrict__ norm_src, float* __restrict__ norm_dst)
{
    int node = blockIdx.x * 256 + threadIdx.x;
    if (node >= N_NODES) return;
    int chunk = (node >= CHUNK_NODES) ? 1 : 0;
    int loc = node - chunk * CHUNK_NODES;
    int w = loc >> 1, sh = (loc & 1) << 4;
    const unsigned* ps = partials + ((size_t)(0 * 2 + chunk) * HB) * CHUNK_WORDS + w;
    const unsigned* pd = partials + ((size_t)(1 * 2 + chunk) * HB) * CHUNK_WORDS + w;
    unsigned so = 0, si = 0;
#pragma unroll 8
    for (int b = 0; b < HB; ++b) {
        so += (ps[(size_t)b * CHUNK_WORDS] >> sh) & 0xFFFFu;
        si += (pd[(size_t)b * CHUNK_WORDS] >> sh) & 0xFFFFu;
    }
    deg_in[node] = (int)si;
    norm_src[node] = so ? (1.0f / sqrtf((float)so)) : 0.0f;
    norm_dst[node] = si ? (1.0f / sqrtf((float)si)) : 0.0f;
}

// -------- exclusive scan of deg_in -> row_start (3 small kernels) ---------

__global__ void scan_phase_a(const int* __restrict__ deg, int* __restrict__ blockSums, int n) {
    __shared__ int s[256];
    int t = threadIdx.x;
    int base = blockIdx.x * 1024 + t * 4;
    int sum = 0;
#pragma unroll
    for (int i = 0; i < 4; ++i) { int idx = base + i; if (idx < n) sum += deg[idx]; }
    s[t] = sum;
    __syncthreads();
    for (int o = 128; o > 0; o >>= 1) {
        if (t < o) s[t] += s[t + o];
        __syncthreads();
    }
    if (t == 0) blockSums[blockIdx.x] = s[0];
}

__global__ void scan_sums(int* __restrict__ blockSums, int nb, int* __restrict__ row_start) {
    if (threadIdx.x == 0 && blockIdx.x == 0) {
        int acc = 0;
        for (int i = 0; i < nb; ++i) { int v = blockSums[i]; blockSums[i] = acc; acc += v; }
        row_start[N_NODES] = acc;   // total == N_EDGES
    }
}

__global__ void scan_phase_b(const int* __restrict__ deg, const int* __restrict__ blockSums,
                             int* __restrict__ row_start, int n) {
    __shared__ int s[256];
    int t = threadIdx.x;
    int base = blockIdx.x * 1024 + t * 4;
    int v[4]; int sum = 0;
#pragma unroll
    for (int i = 0; i < 4; ++i) { int idx = base + i; v[i] = (idx < n) ? deg[idx] : 0; sum += v[i]; }
    s[t] = sum;
    __syncthreads();
    for (int o = 1; o < 256; o <<= 1) {          // Hillis-Steele inclusive scan
        int x = (t >= o) ? s[t - o] : 0;
        __syncthreads();
        s[t] += x;
        __syncthreads();
    }
    int pre = (t > 0 ? s[t - 1] : 0) + blockSums[blockIdx.x];
#pragma unroll
    for (int i = 0; i < 4; ++i) {
        int idx = base + i;
        if (idx < n) { row_start[idx] = pre; pre += v[i]; }
    }
}

__global__ void csr_fill_kernel(const int* __restrict__ src, const int* __restrict__ dst,
                                const int* __restrict__ row_start, int* __restrict__ cursor,
                                const float* __restrict__ norm_src,
                                int* __restrict__ csr_src, float* __restrict__ csr_w) {
    int i = blockIdx.x * blockDim.x + threadIdx.x;
    if (i < N_EDGES) {
        int d = dst[i], s = src[i];
        int p = atomicAdd(&cursor[d], 1);
        int slot = row_start[d] + p;
        csr_src[slot] = s;
        csr_w[slot] = norm_src[s];      // fold D_out^{-1/2} into edge weight
    }
}

// -------------------------------------------- wave-private fused layer
// out[v,:] = relu( (norm_dst[v] * sum_e w_e h[src_e,:]) @ W + b )
// Each wave owns 8 rows end-to-end, NO LDS, NO barriers:
//  1) gather 8 rows into registers. After the shfl_xor(.,32) reduce, ALL
//     64 lanes hold the full row: lane l has agg[r][4*(l&31) .. 4*(l&31)+3].
//  2) vec-mat: lane l produces output cols {2l, 2l+1}. Per k-quad k4 the
//     needed agg[r][k] values live in lane k4 -> __shfl(agg[r].comp, k4)
//     (uniform source, all 64 lanes active -> no exec-mask UB; round-7
//     lesson). W rows are read straight from global: per k a wave reads
//     512 B coalesced; W (64 KB) is L1/L2-resident, reuse x8 rows.
// Gather inner loop identical to the proven split kernel (n8 padding).
__global__ __launch_bounds__(256) void fused_layer_kernel(
    const float* __restrict__ h, const int* __restrict__ csr_src,
    const float* __restrict__ csr_w, const int* __restrict__ row_start,
    const float* __restrict__ norm_dst, const float* __restrict__ W,
    const float* __restrict__ bias, float* __restrict__ out)
{
    int wid = blockIdx.x * 4 + (threadIdx.x >> 6);
    int lane = threadIdx.x & 63;
    int p = lane >> 5, fq = lane & 31;
    int c0 = lane * 2;                        // my two output columns
    const float2 bb = *(const float2*)&bias[c0];
    int nwaves = gridDim.x * 4;

    for (int v0 = wid * 8; v0 < N_NODES; v0 += nwaves * 8) {
        // ---- phase 1: gather 8 rows into registers
        float4 agg[8];
#pragma unroll
        for (int r = 0; r < 8; ++r) {
            int v = v0 + r;
            float4 acc = make_float4(0.f, 0.f, 0.f, 0.f);
            if (v < N_NODES) {               // wave-uniform
                int beg = row_start[v], end = row_start[v + 1];
                for (int base = beg; base < end; base += 64) {
                    int n = min(64, end - base);
                    int sidx = 0; float swt = 0.f;
                    if (lane < n) { sidx = csr_src[base + lane]; swt = csr_w[base + lane]; }
                    int n8 = (n + 7) & ~7;   // uniform trip count for both halves
                    for (int k = p; k < n8; k += 8) {
                        int i0 = __shfl(sidx, k);
                        int i1 = __shfl(sidx, k + 2);
                        int i2 = __shfl(sidx, k + 4);
                        int i3 = __shfl(sidx, k + 6);
                        float w0 = __shfl(swt, k);
                        float w1 = __shfl(swt, k + 2);
                        float w2 = __shfl(swt, k + 4);
                        float w3 = __shfl(swt, k + 6);
                        const float4 a = *(const float4*)&h[(size_t)i0 * DIM + fq * 4];
                        const float4 b = *(const float4*)&h[(size_t)i1 * DIM + fq * 4];
                        const float4 c = *(const float4*)&h[(size_t)i2 * DIM + fq * 4];
                        const float4 d = *(const float4*)&h[(size_t)i3 * DIM + fq * 4];
                        acc.x = fmaf(w0, a.x, acc.x); acc.y = fmaf(w0, a.y, acc.y);
                        acc.z = fmaf(w0, a.z, acc.z); acc.w = fmaf(w0, a.w, acc.w);
                        acc.x = fmaf(w1, b.x, acc.x); acc.y = fmaf(w1, b.y, acc.y);
                        acc.z = fmaf(w1, b.z, acc.z); acc.w = fmaf(w1, b.w, acc.w);
                        acc.x = fmaf(w2, c.x, acc.x); acc.y = fmaf(w2, c.y, acc.y);
                        acc.z = fmaf(w2, c.z, acc.z); acc.w = fmaf(w2, c.w, acc.w);
                        acc.x = fmaf(w3, d.x, acc.x); acc.y = fmaf(w3, d.y, acc.y);
                        acc.z = fmaf(w3, d.z, acc.z); acc.w = fmaf(w3, d.w, acc.w);
                    }
                }
                // both halves end up with the full row sum
                acc.x += __shfl_xor(acc.x, 32);
                acc.y += __shfl_xor(acc.y, 32);
                acc.z += __shfl_xor(acc.z, 32);
                acc.w += __shfl_xor(acc.w, 32);
                float nd = norm_dst[v];
                acc.x *= nd; acc.y *= nd; acc.z *= nd; acc.w *= nd;
            }
            agg[r] = acc;
        }

        // ---- phase 2: 8-row vec-mat against W (cols c0, c0+1 per lane)
        float2 acc2[8];
#pragma unroll
        for (int r = 0; r < 8; ++r) acc2[r] = bb;
#pragma unroll 4
        for (int k4 = 0; k4 < 32; ++k4) {
            const float2 w0 = *(const float2*)&W[(size_t)(4 * k4 + 0) * DIM + c0];
            const float2 w1 = *(const float2*)&W[(size_t)(4 * k4 + 1) * DIM + c0];
            const float2 w2 = *(const float2*)&W[(size_t)(4 * k4 + 2) * DIM + c0];
            const float2 w3 = *(const float2*)&W[(size_t)(4 * k4 + 3) * DIM + c0];
#pragma unroll
            for (int r = 0; r < 8; ++r) {
                float ax = __shfl(agg[r].x, k4);
                float ay = __shfl(agg[r].y, k4);
                float az = __shfl(agg[r].z, k4);
                float aw = __shfl(agg[r].w, k4);
                acc2[r].x = fmaf(ax, w0.x, acc2[r].x);
                acc2[r].y = fmaf(ax, w0.y, acc2[r].y);
                acc2[r].x = fmaf(ay, w1.x, acc2[r].x);
                acc2[r].y = fmaf(ay, w1.y, acc2[r].y);
                acc2[r].x = fmaf(az, w2.x, acc2[r].x);
                acc2[r].y = fmaf(az, w2.y, acc2[r].y);
                acc2[r].x = fmaf(aw, w3.x, acc2[r].x);
                acc2[r].y = fmaf(aw, w3.y, acc2[r].y);
            }
        }
#pragma unroll
        for (int r = 0; r < 8; ++r) {
            int v = v0 + r;
            if (v < N_NODES) {
                float2 o;
                o.x = fmaxf(acc2[r].x, 0.f);
                o.y = fmaxf(acc2[r].y, 0.f);
                *(float2*)&out[(size_t)v * DIM + c0] = o;
            }
        }
    }
}

// ------------------------------------------------------- pooling + classifier
__global__ __launch_bounds__(128) void pool_kernel(
    const float* __restrict__ h, const int* __restrict__ gids,
    const float* __restrict__ Wc, const float* __restrict__ bc,
    float* __restrict__ out /* [0,5000): logits, [5000,69000): hg */)
{
    int g = blockIdx.x;
    int d = threadIdx.x;    // 0..127
    __shared__ int s_beg, s_end;
    __shared__ float s_hg[DIM];
    if (d == 0) {
        int lo = 0, hi = N_NODES;
        while (lo < hi) { int m = (lo + hi) >> 1; if (gids[m] < g) lo = m + 1; else hi = m; }
        s_beg = lo;
        hi = N_NODES;
        while (lo < hi) { int m = (lo + hi) >> 1; if (gids[m] < g + 1) lo = m + 1; else hi = m; }
        s_end = lo;
    }
    __syncthreads();
    int beg = s_beg, end = s_end;
    float acc = 0.f;
    for (int v = beg; v < end; ++v) acc += h[(size_t)v * DIM + d];
    float cnt = (float)(end - beg);
    float hg = acc / fmaxf(cnt, 1.0f);
    out[N_GRAPHS * N_CLASSES + (size_t)g * DIM + d] = hg;
    s_hg[d] = hg;
    __syncthreads();
    if (d < N_CLASSES) {
        float a = bc[d];
        for (int k = 0; k < DIM; ++k) a = fmaf(s_hg[k], Wc[k * N_CLASSES + d], a);
        out[g * N_CLASSES + d] = a;
    }
}

// ---------------------------------------------------------------- launch

extern "C" void kernel_launch(void* const* d_in, const int* in_sizes, int n_in,
                              void* d_out, int out_size, void* d_ws, size_t ws_size,
                              hipStream_t stream)
{
    const float* x   = (const float*)d_in[0];
    const int*   src = (const int*)d_in[1];
    const int*   dst = (const int*)d_in[2];
    const int*   gid = (const int*)d_in[3];
    const float* Wl[4] = { (const float*)d_in[4], (const float*)d_in[6],
                           (const float*)d_in[8], (const float*)d_in[10] };
    const float* bl[4] = { (const float*)d_in[5], (const float*)d_in[7],
                           (const float*)d_in[9], (const float*)d_in[11] };
    const float* Wc = (const float*)d_in[12];
    const float* bc = (const float*)d_in[13];
    float* out = (float*)d_out;

    char* ws = (char*)d_ws;
    size_t off = 0;
    auto alloc = [&](size_t bytes) -> char* {
        char* p = ws + off; off += (bytes + 255) & ~(size_t)255; return p;
    };
    int*   deg_in    = (int*)  alloc((size_t)N_NODES * 4);
    int*   cursor    = (int*)  alloc((size_t)N_NODES * 4);
    float* norm_src  = (float*)alloc((size_t)N_NODES * 4);
    float* norm_dst  = (float*)alloc((size_t)N_NODES * 4);
    int*   row_start = (int*)  alloc((size_t)(N_NODES + 1) * 4);
    int*   blockSums = (int*)  alloc(64 * 4);
    int*   csr_src   = (int*)  alloc((size_t)N_EDGES * 4);
    float* csr_w     = (float*)alloc((size_t)N_EDGES * 4);
    float* buf0      = (float*)alloc((size_t)N_NODES * DIM * 4);
    float* buf1      = (float*)alloc((size_t)N_NODES * DIM * 4);
    if (off > ws_size) return;   // workspace too small -> fail loudly in validation

    // partials (12.8 MB) alias buf1: buf1 is first written at layer 2, long
    // after hist_reduce has consumed the partials.
    unsigned* partials = (unsigned*)buf1;

    zero_kernel<<<(N_NODES + 255) / 256, 256, 0, stream>>>(cursor, N_NODES);

    dim3 hgrid(HB, 2, 2);
    hist_kernel<<<hgrid, 256, 0, stream>>>(src, dst, partials);
    hist_reduce<<<(N_NODES + 255) / 256, 256, 0, stream>>>(partials, deg_in, norm_src, norm_dst);

    int nb = (N_NODES + 1023) / 1024;   // 49
    scan_phase_a<<<nb, 256, 0, stream>>>(deg_in, blockSums, N_NODES);
    scan_sums<<<1, 64, 0, stream>>>(blockSums, nb, row_start);
    scan_phase_b<<<nb, 256, 0, stream>>>(deg_in, blockSums, row_start, N_NODES);

    csr_fill_kernel<<<(N_EDGES + 255) / 256, 256, 0, stream>>>(
        src, dst, row_start, cursor, norm_src, csr_src, csr_w);

    // 6250 wave-batches of 8 rows; 1563 blocks x 4 waves covers them 1:1.
    int fblk = 1563;
    fused_layer_kernel<<<fblk, 256, 0, stream>>>(x,    csr_src, csr_w, row_start, norm_dst, Wl[0], bl[0], buf0);
    fused_layer_kernel<<<fblk, 256, 0, stream>>>(buf0, csr_src, csr_w, row_start, norm_dst, Wl[1], bl[1], buf1);
    fused_layer_kernel<<<fblk, 256, 0, stream>>>(buf1, csr_src, csr_w, row_start, norm_dst, Wl[2], bl[2], buf0);
    fused_layer_kernel<<<fblk, 256, 0, stream>>>(buf0, csr_src, csr_w, row_start, norm_dst, Wl[3], bl[3], buf1);

    pool_kernel<<<N_GRAPHS, DIM, 0, stream>>>(buf1, gid, Wc, bc, out);
}

// Round 14
// 528.472 us; speedup vs baseline: 1.1965x; 1.1965x over previous
//
#include <hip/hip_runtime.h>
#include <math.h>

#define N_NODES   50000
#define N_EDGES   640000
#define N_GRAPHS  500
#define DIM       128
#define N_CLASSES 10

#define HB          64      // edge slices for privatized histogram
#define CHUNK_NODES 25000   // nodes per chunk (2 chunks cover 50000)
#define CHUNK_WORDS 12500   // packed uint16-pair words per chunk (50 KB LDS)

// Privatized histogram: grid (HB, 2 chunks, 2 arrays). Each block histograms
// its 10K-edge slice for one node-chunk of one array into packed LDS
// counters (2 x uint16 per word), then dumps the partial to global.
__global__ __launch_bounds__(256) void hist_kernel(
    const int* __restrict__ src, const int* __restrict__ dst,
    unsigned* __restrict__ partials /* [2 arr][2 chunk][HB][CHUNK_WORDS] */)
{
    __shared__ unsigned hcnt[CHUNK_WORDS];
    int t = threadIdx.x;
    for (int i = t; i < CHUNK_WORDS; i += 256) hcnt[i] = 0;
    __syncthreads();
    const int* arr = blockIdx.z ? dst : src;
    int lo = blockIdx.y * CHUNK_NODES;
    int per = N_EDGES / HB;                  // 10000
    int beg = blockIdx.x * per;
    for (int i = beg + t; i < beg + per; i += 256) {
        int v = arr[i] - lo;
        if ((unsigned)v < (unsigned)CHUNK_NODES)
            atomicAdd(&hcnt[v >> 1], (v & 1) ? 0x10000u : 1u);
    }
    __syncthreads();
    unsigned* outp = partials +
        (((size_t)blockIdx.z * 2 + blockIdx.y) * HB + blockIdx.x) * CHUNK_WORDS;
    for (int i = t; i < CHUNK_WORDS; i += 256) outp[i] = hcnt[i];
}

// Sum partials -> deg_in + both norms; also zero the csr_fill cursor
// (folds the old zero_kernel dispatch into this one).
__global__ __launch_bounds__(256) void hist_reduce(
    const unsigned* __restrict__ partials, int* __restrict__ deg_in,
    float* __restrict__ norm_src, float* __restrict__ norm_dst,
    int* __restrict__ cursor)
{
    int node = blockIdx.x * 256 + threadIdx.x;
    if (node >= N_NODES) return;
    int chunk = (node >= CHUNK_NODES) ? 1 : 0;
    int loc = node - chunk * CHUNK_NODES;
    int w = loc >> 1, sh = (loc & 1) << 4;
    const unsigned* ps = partials + ((size_t)(0 * 2 + chunk) * HB) * CHUNK_WORDS + w;
    const unsigned* pd = partials + ((size_t)(1 * 2 + chunk) * HB) * CHUNK_WORDS + w;
    unsigned so = 0, si = 0;
#pragma unroll 8
    for (int b = 0; b < HB; ++b) {
        so += (ps[(size_t)b * CHUNK_WORDS] >> sh) & 0xFFFFu;
        si += (pd[(size_t)b * CHUNK_WORDS] >> sh) & 0xFFFFu;
    }
    deg_in[node] = (int)si;
    cursor[node] = 0;
    norm_src[node] = so ? (1.0f / sqrtf((float)so)) : 0.0f;
    norm_dst[node] = si ? (1.0f / sqrtf((float)si)) : 0.0f;
}

// Single-block exclusive scan of deg_in -> row_start (replaces 3 dispatches).
// 1024 threads x 49 elements; Hillis-Steele over the 1024 partial sums.
__global__ __launch_bounds__(1024) void scan_kernel(
    const int* __restrict__ deg, int* __restrict__ row_start)
{
    __shared__ int s[1024];
    int t = threadIdx.x;
    const int PER = 49;                      // 1024*49 = 50176 >= 50000
    int lo = t * PER, hi = min(lo + PER, N_NODES);
    int sum = 0;
    for (int i = lo; i < hi; ++i) sum += deg[i];
    s[t] = sum;
    __syncthreads();
    for (int o = 1; o < 1024; o <<= 1) {
        int x = (t >= o) ? s[t - o] : 0;
        __syncthreads();
        s[t] += x;
        __syncthreads();
    }
    int pre = (t > 0) ? s[t - 1] : 0;
    for (int i = lo; i < hi; ++i) { int d = deg[i]; row_start[i] = pre; pre += d; }
    if (t == 1023) row_start[N_NODES] = s[1023];   // total == N_EDGES
}

__global__ void csr_fill_kernel(const int* __restrict__ src, const int* __restrict__ dst,
                                const int* __restrict__ row_start, int* __restrict__ cursor,
                                const float* __restrict__ norm_src,
                                int* __restrict__ csr_src, float* __restrict__ csr_w) {
    int i = blockIdx.x * blockDim.x + threadIdx.x;
    if (i < N_EDGES) {
        int d = dst[i], s = src[i];
        int p = atomicAdd(&cursor[d], 1);
        int slot = row_start[d] + p;
        csr_src[slot] = s;
        csr_w[slot] = norm_src[s];      // fold D_out^{-1/2} into edge weight
    }
}

// ------------------------------------------------- fused gather + GEMM layer
// (round-9 version verbatim — measured best at ~72 us/layer)
// out[v,:] = relu( (norm_dst[v] * sum_e w_e h[src_e,:]) @ W + b )
// Block = 256 thr (4 waves), 32 output rows. Phase 1: wave w gathers rows
// w*8..w*8+7 into sA; half-waves process 4 edges/iter (8 loads in flight).
// Trip count padded to n8 so both half-waves run identical counts with all
// 64 lanes active (shfl from an exec-masked lane is UB on CDNA — round-7).
// Phase 2: 32x128 @ 128x128 GEMM from sA with W staged in 32x128 LDS chunks.
__global__ __launch_bounds__(256) void layer_kernel(
    const float* __restrict__ h, const int* __restrict__ csr_src,
    const float* __restrict__ csr_w, const int* __restrict__ row_start,
    const float* __restrict__ norm_dst, const float* __restrict__ W,
    const float* __restrict__ bias, float* __restrict__ out, int nrows)
{
    __shared__ float sA[32 * DIM];   // 16 KB
    __shared__ float sW[32 * DIM];   // 16 KB
    int tid = threadIdx.x;
    int wave = tid >> 6;             // 0..3
    int lane = tid & 63;
    int p = lane >> 5, fq = lane & 31;
    int row0 = blockIdx.x * 32;

    // ---- Phase 1: gather
    for (int r = 0; r < 8; ++r) {
        int lrow = wave * 8 + r;
        int v = row0 + lrow;
        float4 acc = make_float4(0.f, 0.f, 0.f, 0.f);
        if (v < nrows) {                 // wave-uniform branch
            int beg = row_start[v], end = row_start[v + 1];
            for (int base = beg; base < end; base += 64) {
                int n = min(64, end - base);
                int sidx = 0; float swt = 0.f;
                if (lane < n) { sidx = csr_src[base + lane]; swt = csr_w[base + lane]; }
                int n8 = (n + 7) & ~7;        // uniform trip count for both halves
                for (int k = p; k < n8; k += 8) {
                    int i0 = __shfl(sidx, k);
                    int i1 = __shfl(sidx, k + 2);
                    int i2 = __shfl(sidx, k + 4);
                    int i3 = __shfl(sidx, k + 6);
                    float w0 = __shfl(swt, k);
                    float w1 = __shfl(swt, k + 2);
                    float w2 = __shfl(swt, k + 4);
                    float w3 = __shfl(swt, k + 6);
                    const float4 a = *(const float4*)&h[(size_t)i0 * DIM + fq * 4];
                    const float4 b = *(const float4*)&h[(size_t)i1 * DIM + fq * 4];
                    const float4 c = *(const float4*)&h[(size_t)i2 * DIM + fq * 4];
                    const float4 d = *(const float4*)&h[(size_t)i3 * DIM + fq * 4];
                    acc.x = fmaf(w0, a.x, acc.x); acc.y = fmaf(w0, a.y, acc.y);
                    acc.z = fmaf(w0, a.z, acc.z); acc.w = fmaf(w0, a.w, acc.w);
                    acc.x = fmaf(w1, b.x, acc.x); acc.y = fmaf(w1, b.y, acc.y);
                    acc.z = fmaf(w1, b.z, acc.z); acc.w = fmaf(w1, b.w, acc.w);
                    acc.x = fmaf(w2, c.x, acc.x); acc.y = fmaf(w2, c.y, acc.y);
                    acc.z = fmaf(w2, c.z, acc.z); acc.w = fmaf(w2, c.w, acc.w);
                    acc.x = fmaf(w3, d.x, acc.x); acc.y = fmaf(w3, d.y, acc.y);
                    acc.z = fmaf(w3, d.z, acc.z); acc.w = fmaf(w3, d.w, acc.w);
                }
            }
        }
        acc.x += __shfl_xor(acc.x, 32);
        acc.y += __shfl_xor(acc.y, 32);
        acc.z += __shfl_xor(acc.z, 32);
        acc.w += __shfl_xor(acc.w, 32);
        if (p == 0) {
            float nd = (v < nrows) ? norm_dst[v] : 0.0f;   // also zero-inits tail rows
            *(float4*)&sA[lrow * DIM + fq * 4] =
                make_float4(acc.x * nd, acc.y * nd, acc.z * nd, acc.w * nd);
        }
    }
    __syncthreads();

    // ---- Phase 2: GEMM + bias + relu
    int rq = tid >> 5;       // 0..7  -> rows rq*4 .. rq*4+3
    int cc = tid & 31;       // 0..31 -> cols cc*4 .. cc*4+3
    int r0 = rq * 4, c0 = cc * 4;
    float acc[4][4];
#pragma unroll
    for (int j = 0; j < 4; ++j) {
        float bj = bias[c0 + j];
        acc[0][j] = bj; acc[1][j] = bj; acc[2][j] = bj; acc[3][j] = bj;
    }
#pragma unroll 1
    for (int kb = 0; kb < 4; ++kb) {
        __syncthreads();                 // protect sW from previous chunk's readers
#pragma unroll
        for (int i = 0; i < 4; ++i) {
            int f4 = tid + i * 256;
            int r = f4 >> 5, c4 = f4 & 31;
            *(float4*)&sW[r * DIM + c4 * 4] =
                *(const float4*)&W[(size_t)(kb * 32 + r) * DIM + c4 * 4];
        }
        __syncthreads();
#pragma unroll
        for (int k = 0; k < 32; ++k) {
            float4 w = *(float4*)&sW[k * DIM + c0];
            float a0 = sA[(r0 + 0) * DIM + kb * 32 + k];
            float a1 = sA[(r0 + 1) * DIM + kb * 32 + k];
            float a2 = sA[(r0 + 2) * DIM + kb * 32 + k];
            float a3 = sA[(r0 + 3) * DIM + kb * 32 + k];
            acc[0][0] = fmaf(a0, w.x, acc[0][0]); acc[0][1] = fmaf(a0, w.y, acc[0][1]);
            acc[0][2] = fmaf(a0, w.z, acc[0][2]); acc[0][3] = fmaf(a0, w.w, acc[0][3]);
            acc[1][0] = fmaf(a1, w.x, acc[1][0]); acc[1][1] = fmaf(a1, w.y, acc[1][1]);
            acc[1][2] = fmaf(a1, w.z, acc[1][2]); acc[1][3] = fmaf(a1, w.w, acc[1][3]);
            acc[2][0] = fmaf(a2, w.x, acc[2][0]); acc[2][1] = fmaf(a2, w.y, acc[2][1]);
            acc[2][2] = fmaf(a2, w.z, acc[2][2]); acc[2][3] = fmaf(a2, w.w, acc[2][3]);
            acc[3][0] = fmaf(a3, w.x, acc[3][0]); acc[3][1] = fmaf(a3, w.y, acc[3][1]);
            acc[3][2] = fmaf(a3, w.z, acc[3][2]); acc[3][3] = fmaf(a3, w.w, acc[3][3]);
        }
    }
#pragma unroll
    for (int i = 0; i < 4; ++i) {
        int r = row0 + r0 + i;
        if (r < nrows) {
            float4 o;
            o.x = fmaxf(acc[i][0], 0.f);
            o.y = fmaxf(acc[i][1], 0.f);
            o.z = fmaxf(acc[i][2], 0.f);
            o.w = fmaxf(acc[i][3], 0.f);
            *(float4*)&out[(size_t)r * DIM + c0] = o;
        }
    }
}

// ------------------------------------------------------- pooling + classifier
__global__ __launch_bounds__(128) void pool_kernel(
    const float* __restrict__ h, const int* __restrict__ gids,
    const float* __restrict__ Wc, const float* __restrict__ bc,
    float* __restrict__ out /* [0,5000): logits, [5000,69000): hg */)
{
    int g = blockIdx.x;
    int d = threadIdx.x;    // 0..127
    __shared__ int s_beg, s_end;
    __shared__ float s_hg[DIM];
    if (d == 0) {
        int lo = 0, hi = N_NODES;
        while (lo < hi) { int m = (lo + hi) >> 1; if (gids[m] < g) lo = m + 1; else hi = m; }
        s_beg = lo;
        hi = N_NODES;
        while (lo < hi) { int m = (lo + hi) >> 1; if (gids[m] < g + 1) lo = m + 1; else hi = m; }
        s_end = lo;
    }
    __syncthreads();
    int beg = s_beg, end = s_end;
    float acc = 0.f;
    for (int v = beg; v < end; ++v) acc += h[(size_t)v * DIM + d];
    float cnt = (float)(end - beg);
    float hg = acc / fmaxf(cnt, 1.0f);
    out[N_GRAPHS * N_CLASSES + (size_t)g * DIM + d] = hg;
    s_hg[d] = hg;
    __syncthreads();
    if (d < N_CLASSES) {
        float a = bc[d];
        for (int k = 0; k < DIM; ++k) a = fmaf(s_hg[k], Wc[k * N_CLASSES + d], a);
        out[g * N_CLASSES + d] = a;
    }
}

// ---------------------------------------------------------------- launch

extern "C" void kernel_launch(void* const* d_in, const int* in_sizes, int n_in,
                              void* d_out, int out_size, void* d_ws, size_t ws_size,
                              hipStream_t stream)
{
    const float* x   = (const float*)d_in[0];
    const int*   src = (const int*)d_in[1];
    const int*   dst = (const int*)d_in[2];
    const int*   gid = (const int*)d_in[3];
    const float* Wl[4] = { (const float*)d_in[4], (const float*)d_in[6],
                           (const float*)d_in[8], (const float*)d_in[10] };
    const float* bl[4] = { (const float*)d_in[5], (const float*)d_in[7],
                           (const float*)d_in[9], (const float*)d_in[11] };
    const float* Wc = (const float*)d_in[12];
    const float* bc = (const float*)d_in[13];
    float* out = (float*)d_out;

    char* ws = (char*)d_ws;
    size_t off = 0;
    auto alloc = [&](size_t bytes) -> char* {
        char* p = ws + off; off += (bytes + 255) & ~(size_t)255; return p;
    };
    int*   deg_in    = (int*)  alloc((size_t)N_NODES * 4);
    int*   cursor    = (int*)  alloc((size_t)N_NODES * 4);
    float* norm_src  = (float*)alloc((size_t)N_NODES * 4);
    float* norm_dst  = (float*)alloc((size_t)N_NODES * 4);
    int*   row_start = (int*)  alloc((size_t)(N_NODES + 1) * 4);
    int*   csr_src   = (int*)  alloc((size_t)N_EDGES * 4);
    float* csr_w     = (float*)alloc((size_t)N_EDGES * 4);
    float* buf0      = (float*)alloc((size_t)N_NODES * DIM * 4);
    float* buf1      = (float*)alloc((size_t)N_NODES * DIM * 4);
    if (off > ws_size) return;   // workspace too small -> fail loudly in validation

    // partials (12.8 MB) alias buf1: buf1 is first written at layer 2, long
    // after hist_reduce has consumed the partials.
    unsigned* partials = (unsigned*)buf1;

    dim3 hgrid(HB, 2, 2);
    hist_kernel<<<hgrid, 256, 0, stream>>>(src, dst, partials);
    hist_reduce<<<(N_NODES + 255) / 256, 256, 0, stream>>>(
        partials, deg_in, norm_src, norm_dst, cursor);

    scan_kernel<<<1, 1024, 0, stream>>>(deg_in, row_start);

    csr_fill_kernel<<<(N_EDGES + 255) / 256, 256, 0, stream>>>(
        src, dst, row_start, cursor, norm_src, csr_src, csr_w);

    int nblk = (N_NODES + 31) / 32;   // 1563
    layer_kernel<<<nblk, 256, 0, stream>>>(x,    csr_src, csr_w, row_start, norm_dst, Wl[0], bl[0], buf0, N_NODES);
    layer_kernel<<<nblk, 256, 0, stream>>>(buf0, csr_src, csr_w, row_start, norm_dst, Wl[1], bl[1], buf1, N_NODES);
    layer_kernel<<<nblk, 256, 0, stream>>>(buf1, csr_src, csr_w, row_start, norm_dst, Wl[2], bl[2], buf0, N_NODES);
    layer_kernel<<<nblk, 256, 0, stream>>>(buf0, csr_src, csr_w, row_start, norm_dst, Wl[3], bl[3], buf1, N_NODES);

    pool_kernel<<<N_GRAPHS, DIM, 0, stream>>>(buf1, gid, Wc, bc, out);
}

// Round 15
// 463.335 us; speedup vs baseline: 1.3647x; 1.1406x over previous
//
#include <hip/hip_runtime.h>
#include <math.h>

#define N_NODES   50000
#define N_EDGES   640000
#define N_GRAPHS  500
#define DIM       128
#define N_CLASSES 10

#define HB          64      // edge slices for privatized histogram
#define CHUNK_NODES 25000   // nodes per chunk (2 chunks cover 50000)
#define CHUNK_WORDS 12500   // packed uint16-pair words per chunk (50 KB LDS)

// Privatized histogram: grid (HB, 2 chunks, 2 arrays). Each block histograms
// its 10K-edge slice for one node-chunk of one array into packed LDS
// counters (2 x uint16 per word), then dumps the partial to global.
__global__ __launch_bounds__(256) void hist_kernel(
    const int* __restrict__ src, const int* __restrict__ dst,
    unsigned* __restrict__ partials /* [2 arr][2 chunk][HB][CHUNK_WORDS] */)
{
    __shared__ unsigned hcnt[CHUNK_WORDS];
    int t = threadIdx.x;
    for (int i = t; i < CHUNK_WORDS; i += 256) hcnt[i] = 0;
    __syncthreads();
    const int* arr = blockIdx.z ? dst : src;
    int lo = blockIdx.y * CHUNK_NODES;
    int per = N_EDGES / HB;                  // 10000
    int beg = blockIdx.x * per;
    for (int i = beg + t; i < beg + per; i += 256) {
        int v = arr[i] - lo;
        if ((unsigned)v < (unsigned)CHUNK_NODES)
            atomicAdd(&hcnt[v >> 1], (v & 1) ? 0x10000u : 1u);
    }
    __syncthreads();
    unsigned* outp = partials +
        (((size_t)blockIdx.z * 2 + blockIdx.y) * HB + blockIdx.x) * CHUNK_WORDS;
    for (int i = t; i < CHUNK_WORDS; i += 256) outp[i] = hcnt[i];
}

// Sum partials -> deg_in + both norms; also zero the csr_fill cursor
// (folds the old zero_kernel dispatch into this one — the one consolidation
// from round 13 that was actually free).
__global__ __launch_bounds__(256) void hist_reduce(
    const unsigned* __restrict__ partials, int* __restrict__ deg_in,
    float* __restrict__ norm_src, float* __restrict__ norm_dst,
    int* __restrict__ cursor)
{
    int node = blockIdx.x * 256 + threadIdx.x;
    if (node >= N_NODES) return;
    int chunk = (node >= CHUNK_NODES) ? 1 : 0;
    int loc = node - chunk * CHUNK_NODES;
    int w = loc >> 1, sh = (loc & 1) << 4;
    const unsigned* ps = partials + ((size_t)(0 * 2 + chunk) * HB) * CHUNK_WORDS + w;
    const unsigned* pd = partials + ((size_t)(1 * 2 + chunk) * HB) * CHUNK_WORDS + w;
    unsigned so = 0, si = 0;
#pragma unroll 8
    for (int b = 0; b < HB; ++b) {
        so += (ps[(size_t)b * CHUNK_WORDS] >> sh) & 0xFFFFu;
        si += (pd[(size_t)b * CHUNK_WORDS] >> sh) & 0xFFFFu;
    }
    deg_in[node] = (int)si;
    cursor[node] = 0;
    norm_src[node] = so ? (1.0f / sqrtf((float)so)) : 0.0f;
    norm_dst[node] = si ? (1.0f / sqrtf((float)si)) : 0.0f;
}

// -------- exclusive scan of deg_in -> row_start (3 small kernels) ---------
// (round-9 proven version: multi-block, coalesced — the round-13 single-block
// scan ran on ONE CU with uncoalesced loads and cost 77 us. Lesson: never
// trade 255 idle CUs for one saved ~2us dispatch gap.)

__global__ void scan_phase_a(const int* __restrict__ deg, int* __restrict__ blockSums, int n) {
    __shared__ int s[256];
    int t = threadIdx.x;
    int base = blockIdx.x * 1024 + t * 4;
    int sum = 0;
#pragma unroll
    for (int i = 0; i < 4; ++i) { int idx = base + i; if (idx < n) sum += deg[idx]; }
    s[t] = sum;
    __syncthreads();
    for (int o = 128; o > 0; o >>= 1) {
        if (t < o) s[t] += s[t + o];
        __syncthreads();
    }
    if (t == 0) blockSums[blockIdx.x] = s[0];
}

__global__ void scan_sums(int* __restrict__ blockSums, int nb, int* __restrict__ row_start) {
    if (threadIdx.x == 0 && blockIdx.x == 0) {
        int acc = 0;
        for (int i = 0; i < nb; ++i) { int v = blockSums[i]; blockSums[i] = acc; acc += v; }
        row_start[N_NODES] = acc;   // total == N_EDGES
    }
}

__global__ void scan_phase_b(const int* __restrict__ deg, const int* __restrict__ blockSums,
                             int* __restrict__ row_start, int n) {
    __shared__ int s[256];
    int t = threadIdx.x;
    int base = blockIdx.x * 1024 + t * 4;
    int v[4]; int sum = 0;
#pragma unroll
    for (int i = 0; i < 4; ++i) { int idx = base + i; v[i] = (idx < n) ? deg[idx] : 0; sum += v[i]; }
    s[t] = sum;
    __syncthreads();
    for (int o = 1; o < 256; o <<= 1) {          // Hillis-Steele inclusive scan
        int x = (t >= o) ? s[t - o] : 0;
        __syncthreads();
        s[t] += x;
        __syncthreads();
    }
    int pre = (t > 0 ? s[t - 1] : 0) + blockSums[blockIdx.x];
#pragma unroll
    for (int i = 0; i < 4; ++i) {
        int idx = base + i;
        if (idx < n) { row_start[idx] = pre; pre += v[i]; }
    }
}

__global__ void csr_fill_kernel(const int* __restrict__ src, const int* __restrict__ dst,
                                const int* __restrict__ row_start, int* __restrict__ cursor,
                                const float* __restrict__ norm_src,
                                int* __restrict__ csr_src, float* __restrict__ csr_w) {
    int i = blockIdx.x * blockDim.x + threadIdx.x;
    if (i < N_EDGES) {
        int d = dst[i], s = src[i];
        int p = atomicAdd(&cursor[d], 1);
        int slot = row_start[d] + p;
        csr_src[slot] = s;
        csr_w[slot] = norm_src[s];      // fold D_out^{-1/2} into edge weight
    }
}

// ------------------------------------------------- fused gather + GEMM layer
// (round-9 version verbatim — measured best at ~72 us/layer)
// out[v,:] = relu( (norm_dst[v] * sum_e w_e h[src_e,:]) @ W + b )
// Block = 256 thr (4 waves), 32 output rows. Phase 1: wave w gathers rows
// w*8..w*8+7 into sA; half-waves process 4 edges/iter (8 loads in flight).
// Trip count padded to n8 so both half-waves run identical counts with all
// 64 lanes active (shfl from an exec-masked lane is UB on CDNA — round-7).
// Phase 2: 32x128 @ 128x128 GEMM from sA with W staged in 32x128 LDS chunks.
__global__ __launch_bounds__(256) void layer_kernel(
    const float* __restrict__ h, const int* __restrict__ csr_src,
    const float* __restrict__ csr_w, const int* __restrict__ row_start,
    const float* __restrict__ norm_dst, const float* __restrict__ W,
    const float* __restrict__ bias, float* __restrict__ out, int nrows)
{
    __shared__ float sA[32 * DIM];   // 16 KB
    __shared__ float sW[32 * DIM];   // 16 KB
    int tid = threadIdx.x;
    int wave = tid >> 6;             // 0..3
    int lane = tid & 63;
    int p = lane >> 5, fq = lane & 31;
    int row0 = blockIdx.x * 32;

    // ---- Phase 1: gather
    for (int r = 0; r < 8; ++r) {
        int lrow = wave * 8 + r;
        int v = row0 + lrow;
        float4 acc = make_float4(0.f, 0.f, 0.f, 0.f);
        if (v < nrows) {                 // wave-uniform branch
            int beg = row_start[v], end = row_start[v + 1];
            for (int base = beg; base < end; base += 64) {
                int n = min(64, end - base);
                int sidx = 0; float swt = 0.f;
                if (lane < n) { sidx = csr_src[base + lane]; swt = csr_w[base + lane]; }
                int n8 = (n + 7) & ~7;        // uniform trip count for both halves
                for (int k = p; k < n8; k += 8) {
                    int i0 = __shfl(sidx, k);
                    int i1 = __shfl(sidx, k + 2);
                    int i2 = __shfl(sidx, k + 4);
                    int i3 = __shfl(sidx, k + 6);
                    float w0 = __shfl(swt, k);
                    float w1 = __shfl(swt, k + 2);
                    float w2 = __shfl(swt, k + 4);
                    float w3 = __shfl(swt, k + 6);
                    const float4 a = *(const float4*)&h[(size_t)i0 * DIM + fq * 4];
                    const float4 b = *(const float4*)&h[(size_t)i1 * DIM + fq * 4];
                    const float4 c = *(const float4*)&h[(size_t)i2 * DIM + fq * 4];
                    const float4 d = *(const float4*)&h[(size_t)i3 * DIM + fq * 4];
                    acc.x = fmaf(w0, a.x, acc.x); acc.y = fmaf(w0, a.y, acc.y);
                    acc.z = fmaf(w0, a.z, acc.z); acc.w = fmaf(w0, a.w, acc.w);
                    acc.x = fmaf(w1, b.x, acc.x); acc.y = fmaf(w1, b.y, acc.y);
                    acc.z = fmaf(w1, b.z, acc.z); acc.w = fmaf(w1, b.w, acc.w);
                    acc.x = fmaf(w2, c.x, acc.x); acc.y = fmaf(w2, c.y, acc.y);
                    acc.z = fmaf(w2, c.z, acc.z); acc.w = fmaf(w2, c.w, acc.w);
                    acc.x = fmaf(w3, d.x, acc.x); acc.y = fmaf(w3, d.y, acc.y);
                    acc.z = fmaf(w3, d.z, acc.z); acc.w = fmaf(w3, d.w, acc.w);
                }
            }
        }
        acc.x += __shfl_xor(acc.x, 32);
        acc.y += __shfl_xor(acc.y, 32);
        acc.z += __shfl_xor(acc.z, 32);
        acc.w += __shfl_xor(acc.w, 32);
        if (p == 0) {
            float nd = (v < nrows) ? norm_dst[v] : 0.0f;   // also zero-inits tail rows
            *(float4*)&sA[lrow * DIM + fq * 4] =
                make_float4(acc.x * nd, acc.y * nd, acc.z * nd, acc.w * nd);
        }
    }
    __syncthreads();

    // ---- Phase 2: GEMM + bias + relu
    int rq = tid >> 5;       // 0..7  -> rows rq*4 .. rq*4+3
    int cc = tid & 31;       // 0..31 -> cols cc*4 .. cc*4+3
    int r0 = rq * 4, c0 = cc * 4;
    float acc[4][4];
#pragma unroll
    for (int j = 0; j < 4; ++j) {
        float bj = bias[c0 + j];
        acc[0][j] = bj; acc[1][j] = bj; acc[2][j] = bj; acc[3][j] = bj;
    }
#pragma unroll 1
    for (int kb = 0; kb < 4; ++kb) {
        __syncthreads();                 // protect sW from previous chunk's readers
#pragma unroll
        for (int i = 0; i < 4; ++i) {
            int f4 = tid + i * 256;
            int r = f4 >> 5, c4 = f4 & 31;
            *(float4*)&sW[r * DIM + c4 * 4] =
                *(const float4*)&W[(size_t)(kb * 32 + r) * DIM + c4 * 4];
        }
        __syncthreads();
#pragma unroll
        for (int k = 0; k < 32; ++k) {
            float4 w = *(float4*)&sW[k * DIM + c0];
            float a0 = sA[(r0 + 0) * DIM + kb * 32 + k];
            float a1 = sA[(r0 + 1) * DIM + kb * 32 + k];
            float a2 = sA[(r0 + 2) * DIM + kb * 32 + k];
            float a3 = sA[(r0 + 3) * DIM + kb * 32 + k];
            acc[0][0] = fmaf(a0, w.x, acc[0][0]); acc[0][1] = fmaf(a0, w.y, acc[0][1]);
            acc[0][2] = fmaf(a0, w.z, acc[0][2]); acc[0][3] = fmaf(a0, w.w, acc[0][3]);
            acc[1][0] = fmaf(a1, w.x, acc[1][0]); acc[1][1] = fmaf(a1, w.y, acc[1][1]);
            acc[1][2] = fmaf(a1, w.z, acc[1][2]); acc[1][3] = fmaf(a1, w.w, acc[1][3]);
            acc[2][0] = fmaf(a2, w.x, acc[2][0]); acc[2][1] = fmaf(a2, w.y, acc[2][1]);
            acc[2][2] = fmaf(a2, w.z, acc[2][2]); acc[2][3] = fmaf(a2, w.w, acc[2][3]);
            acc[3][0] = fmaf(a3, w.x, acc[3][0]); acc[3][1] = fmaf(a3, w.y, acc[3][1]);
            acc[3][2] = fmaf(a3, w.z, acc[3][2]); acc[3][3] = fmaf(a3, w.w, acc[3][3]);
        }
    }
#pragma unroll
    for (int i = 0; i < 4; ++i) {
        int r = row0 + r0 + i;
        if (r < nrows) {
            float4 o;
            o.x = fmaxf(acc[i][0], 0.f);
            o.y = fmaxf(acc[i][1], 0.f);
            o.z = fmaxf(acc[i][2], 0.f);
            o.w = fmaxf(acc[i][3], 0.f);
            *(float4*)&out[(size_t)r * DIM + c0] = o;
        }
    }
}

// ------------------------------------------------------- pooling + classifier
__global__ __launch_bounds__(128) void pool_kernel(
    const float* __restrict__ h, const int* __restrict__ gids,
    const float* __restrict__ Wc, const float* __restrict__ bc,
    float* __restrict__ out /* [0,5000): logits, [5000,69000): hg */)
{
    int g = blockIdx.x;
    int d = threadIdx.x;    // 0..127
    __shared__ int s_beg, s_end;
    __shared__ float s_hg[DIM];
    if (d == 0) {
        int lo = 0, hi = N_NODES;
        while (lo < hi) { int m = (lo + hi) >> 1; if (gids[m] < g) lo = m + 1; else hi = m; }
        s_beg = lo;
        hi = N_NODES;
        while (lo < hi) { int m = (lo + hi) >> 1; if (gids[m] < g + 1) lo = m + 1; else hi = m; }
        s_end = lo;
    }
    __syncthreads();
    int beg = s_beg, end = s_end;
    float acc = 0.f;
    for (int v = beg; v < end; ++v) acc += h[(size_t)v * DIM + d];
    float cnt = (float)(end - beg);
    float hg = acc / fmaxf(cnt, 1.0f);
    out[N_GRAPHS * N_CLASSES + (size_t)g * DIM + d] = hg;
    s_hg[d] = hg;
    __syncthreads();
    if (d < N_CLASSES) {
        float a = bc[d];
        for (int k = 0; k < DIM; ++k) a = fmaf(s_hg[k], Wc[k * N_CLASSES + d], a);
        out[g * N_CLASSES + d] = a;
    }
}

// ---------------------------------------------------------------- launch

extern "C" void kernel_launch(void* const* d_in, const int* in_sizes, int n_in,
                              void* d_out, int out_size, void* d_ws, size_t ws_size,
                              hipStream_t stream)
{
    const float* x   = (const float*)d_in[0];
    const int*   src = (const int*)d_in[1];
    const int*   dst = (const int*)d_in[2];
    const int*   gid = (const int*)d_in[3];
    const float* Wl[4] = { (const float*)d_in[4], (const float*)d_in[6],
                           (const float*)d_in[8], (const float*)d_in[10] };
    const float* bl[4] = { (const float*)d_in[5], (const float*)d_in[7],
                           (const float*)d_in[9], (const float*)d_in[11] };
    const float* Wc = (const float*)d_in[12];
    const float* bc = (const float*)d_in[13];
    float* out = (float*)d_out;

    char* ws = (char*)d_ws;
    size_t off = 0;
    auto alloc = [&](size_t bytes) -> char* {
        char* p = ws + off; off += (bytes + 255) & ~(size_t)255; return p;
    };
    int*   deg_in    = (int*)  alloc((size_t)N_NODES * 4);
    int*   cursor    = (int*)  alloc((size_t)N_NODES * 4);
    float* norm_src  = (float*)alloc((size_t)N_NODES * 4);
    float* norm_dst  = (float*)alloc((size_t)N_NODES * 4);
    int*   row_start = (int*)  alloc((size_t)(N_NODES + 1) * 4);
    int*   blockSums = (int*)  alloc(64 * 4);
    int*   csr_src   = (int*)  alloc((size_t)N_EDGES * 4);
    float* csr_w     = (float*)alloc((size_t)N_EDGES * 4);
    float* buf0      = (float*)alloc((size_t)N_NODES * DIM * 4);
    float* buf1      = (float*)alloc((size_t)N_NODES * DIM * 4);
    if (off > ws_size) return;   // workspace too small -> fail loudly in validation

    // partials (12.8 MB) alias buf1: buf1 is first written at layer 2, long
    // after hist_reduce has consumed the partials.
    unsigned* partials = (unsigned*)buf1;

    dim3 hgrid(HB, 2, 2);
    hist_kernel<<<hgrid, 256, 0, stream>>>(src, dst, partials);
    hist_reduce<<<(N_NODES + 255) / 256, 256, 0, stream>>>(
        partials, deg_in, norm_src, norm_dst, cursor);

    int nb = (N_NODES + 1023) / 1024;   // 49
    scan_phase_a<<<nb, 256, 0, stream>>>(deg_in, blockSums, N_NODES);
    scan_sums<<<1, 64, 0, stream>>>(blockSums, nb, row_start);
    scan_phase_b<<<nb, 256, 0, stream>>>(deg_in, blockSums, row_start, N_NODES);

    csr_fill_kernel<<<(N_EDGES + 255) / 256, 256, 0, stream>>>(
        src, dst, row_start, cursor, norm_src, csr_src, csr_w);

    int nblk = (N_NODES + 31) / 32;   // 1563
    layer_kernel<<<nblk, 256, 0, stream>>>(x,    csr_src, csr_w, row_start, norm_dst, Wl[0], bl[0], buf0, N_NODES);
    layer_kernel<<<nblk, 256, 0, stream>>>(buf0, csr_src, csr_w, row_start, norm_dst, Wl[1], bl[1], buf1, N_NODES);
    layer_kernel<<<nblk, 256, 0, stream>>>(buf1, csr_src, csr_w, row_start, norm_dst, Wl[2], bl[2], buf0, N_NODES);
    layer_kernel<<<nblk, 256, 0, stream>>>(buf0, csr_src, csr_w, row_start, norm_dst, Wl[3], bl[3], buf1, N_NODES);

    pool_kernel<<<N_GRAPHS, DIM, 0, stream>>>(buf1, gid, Wc, bc, out);
}